// Round 1
// baseline (1116.635 us; speedup 1.0000x reference)
//
#include <hip/hip_runtime.h>
#include <math.h>

// Problem constants
// BATCH=128, IN_CH=OUT_CH=64, DIM=4096, HALF=2049 (=MODES)
#define NFFT   4096
#define HALF   2049
#define NSIG   8192      // 128*64
#define NIO    4096      // 64*64

__device__ __forceinline__ float2 cmulf(float2 a, float2 b) {
  return make_float2(a.x*b.x - a.y*b.y, a.x*b.y + a.y*b.x);
}

// ---------------- K1: rfft(4096) via full complex Stockham FFT + phase align ----------------
__global__ __launch_bounds__(256) void k_rfft_phase(
    const float* __restrict__ x, float2* __restrict__ z, float* __restrict__ phi0) {
  __shared__ float2 bufA[NFFT];
  __shared__ float2 bufB[NFFT];
  const int bi  = blockIdx.x;        // b*64 + i
  const int tid = threadIdx.x;
  const float* xp = x + (size_t)bi * NFFT;
  for (int j = tid; j < NFFT; j += 256) bufA[j] = make_float2(xp[j], 0.0f);
  __syncthreads();

  float2* src = bufA; float2* dst = bufB;
  #pragma unroll 1
  for (int st = 0; st < 12; ++st) {
    const int n  = NFFT >> st;           // current transform length
    const float tw = -6.2831853071795864f / (float)n;  // forward: e^{-2pi i p/n}
    #pragma unroll
    for (int jj = 0; jj < 8; ++jj) {
      const int j = tid + jj * 256;      // j in [0, 2048)
      const int p = j >> st;             // p in [0, n/2)
      const int q = j & ((1 << st) - 1); // q in [0, s),  s = 1<<st
      float2 a = src[q + (p << st)];
      float2 b = src[q + (p << st) + 2048];   // s*(p+m), s*m == 2048 always
      float sn, cs; __sincosf(tw * (float)p, &sn, &cs);
      float2 dif = make_float2(a.x - b.x, a.y - b.y);
      dst[q + (p << (st + 1))]             = make_float2(a.x + b.x, a.y + b.y);
      dst[q + (p << (st + 1)) + (1 << st)] = make_float2(dif.x*cs - dif.y*sn, dif.x*sn + dif.y*cs);
    }
    __syncthreads();
    float2* t = src; src = dst; dst = t;
  }
  // 12 stages (even) -> result back in bufA == src, natural order.
  const float2 z1 = src[1];
  const float phi = atan2f(z1.y, z1.x);
  if (tid == 0 && (bi & 63) == 0) phi0[bi >> 6] = phi;  // channel i==0 -> phi0[b]

  const double inv2pi = 0.15915494309189535;
  for (int k = tid; k < HALF; k += 256) {
    const int kin = (k <= 1024) ? k : k - HALF;   // fftfreq(2049)*2049 integers
    double rev = (double)phi * (double)kin * inv2pi;
    rev -= rint(rev);                              // exact-ish mod-2pi reduction
    const float th = (float)(rev * 6.283185307179586);
    float sn, cs; __sincosf(th, &sn, &cs);
    // multiply by e^{-i th} = (cs, -sn)
    const float2 Zk = src[k];
    z[(size_t)bi * HALF + k] = make_float2(Zk.x*cs + Zk.y*sn, Zk.y*cs - Zk.x*sn);
  }
}

// ---------------- generic float2 tiled transpose: in R x C  ->  out C x R ----------------
__global__ __launch_bounds__(256) void k_transpose_f2(
    const float2* __restrict__ in, float2* __restrict__ out, int R, int C) {
  __shared__ float2 tile[32][33];
  const int tx = threadIdx.x & 31, ty = threadIdx.x >> 5;   // ty in 0..7
  const int c0 = blockIdx.x * 32, r0 = blockIdx.y * 32;
  #pragma unroll
  for (int dy = 0; dy < 32; dy += 8) {
    const int r = r0 + ty + dy, c = c0 + tx;
    if (r < R && c < C) tile[ty + dy][tx] = in[(size_t)r * C + c];
  }
  __syncthreads();
  #pragma unroll
  for (int dy = 0; dy < 32; dy += 8) {
    const int r = c0 + ty + dy, c = r0 + tx;
    if (r < C && c < R) out[(size_t)r * R + c] = tile[tx][ty + dy];
  }
}

// ---------------- w transpose: (io, k) two float arrays -> (k, io) float2 ----------------
__global__ __launch_bounds__(256) void k_transpose_w(
    const float* __restrict__ wr, const float* __restrict__ wi,
    float2* __restrict__ out, int R, int C) {
  __shared__ float2 tile[32][33];
  const int tx = threadIdx.x & 31, ty = threadIdx.x >> 5;
  const int c0 = blockIdx.x * 32, r0 = blockIdx.y * 32;
  #pragma unroll
  for (int dy = 0; dy < 32; dy += 8) {
    const int r = r0 + ty + dy, c = c0 + tx;
    if (r < R && c < C) {
      const size_t idx = (size_t)r * C + c;
      tile[ty + dy][tx] = make_float2(wr[idx], wi[idx]);
    }
  }
  __syncthreads();
  #pragma unroll
  for (int dy = 0; dy < 32; dy += 8) {
    const int r = c0 + ty + dy, c = r0 + tx;
    if (r < C && c < R) out[(size_t)r * R + c] = tile[tx][ty + dy];
  }
}

// ---------------- K3: per-mode complex GEMM + bias + e^{+i phi0 k_out} ----------------
// zt: [k][8192] (b*64+i),  wt: [k][4096] (i*64+o),  oft: [k][8192] (b*64+o)
__global__ __launch_bounds__(256) void k_gemm_mode(
    const float2* __restrict__ zt, const float2* __restrict__ wt,
    const float* __restrict__ br, const float* __restrict__ bim,
    const float* __restrict__ phi0, float2* __restrict__ oft) {
  __shared__ float2 zl[32][129];   // [ic][b], padded
  __shared__ float2 wl[32][64];    // [ic][o]
  const int k = blockIdx.x, t = threadIdx.x;
  const int og = t & 15, bg = t >> 4;
  const int o0 = og * 4, b0 = bg * 8;
  float2 acc[8][4];
  #pragma unroll
  for (int j = 0; j < 8; ++j)
    #pragma unroll
    for (int m = 0; m < 4; ++m) acc[j][m] = make_float2(0.f, 0.f);

  const float2* zrow = zt + (size_t)k * NSIG;
  const float2* wrow = wt + (size_t)k * NIO;

  #pragma unroll 1
  for (int ih = 0; ih < 2; ++ih) {
    for (int l = t; l < 128 * 32; l += 256) {
      const int b = l >> 5, ic = l & 31;
      zl[ic][b] = zrow[b * 64 + ih * 32 + ic];
    }
    for (int l = t; l < 32 * 64; l += 256) {
      const int ic = l >> 6, o = l & 63;
      wl[ic][o] = wrow[(ih * 32 + ic) * 64 + o];
    }
    __syncthreads();
    #pragma unroll 4
    for (int ic = 0; ic < 32; ++ic) {
      float2 wv[4];
      #pragma unroll
      for (int m = 0; m < 4; ++m) wv[m] = wl[ic][o0 + m];
      #pragma unroll
      for (int j = 0; j < 8; ++j) {
        const float2 zv = zl[ic][b0 + j];
        #pragma unroll
        for (int m = 0; m < 4; ++m) {
          acc[j][m].x += zv.x * wv[m].x - zv.y * wv[m].y;
          acc[j][m].y += zv.x * wv[m].y + zv.y * wv[m].x;
        }
      }
    }
    __syncthreads();
  }

  // epilogue: bias + rotation by e^{+i phi0[b] * k_out}
  const int kout = (k <= 1024) ? k : k - HALF;
  float2 rot[8];
  #pragma unroll
  for (int j = 0; j < 8; ++j) {
    double rev = (double)phi0[b0 + j] * (double)kout * 0.15915494309189535;
    rev -= rint(rev);
    const float th = (float)(rev * 6.283185307179586);
    float sn, cs; __sincosf(th, &sn, &cs);
    rot[j] = make_float2(cs, sn);
  }
  #pragma unroll
  for (int m = 0; m < 4; ++m) {
    const int o = o0 + m;
    const float2 bia = make_float2(br[(size_t)o * HALF + k], bim[(size_t)o * HALF + k]);
    #pragma unroll
    for (int j = 0; j < 8; ++j) {
      const float2 v = make_float2(acc[j][m].x + bia.x, acc[j][m].y + bia.y);
      oft[(size_t)k * NSIG + (size_t)(b0 + j) * 64 + o] = cmulf(v, rot[j]);
    }
  }
}

// ---------------- K5: irfft(4096): Hermitian extend + inverse Stockham FFT ----------------
__global__ __launch_bounds__(256) void k_irfft(
    const float2* __restrict__ oft, float* __restrict__ out) {
  __shared__ float2 bufA[NFFT];
  __shared__ float2 bufB[NFFT];
  const int bo  = blockIdx.x;     // b*64 + o
  const int tid = threadIdx.x;
  const float2* ip = oft + (size_t)bo * HALF;
  for (int k = tid; k < HALF; k += 256) {
    const float2 v = ip[k];
    if (k == 0 || k == 2048) {
      bufA[k] = make_float2(v.x, 0.0f);     // numpy c2r drops imag of DC/Nyquist
    } else {
      bufA[k]        = v;
      bufA[NFFT - k] = make_float2(v.x, -v.y);
    }
  }
  __syncthreads();

  float2* src = bufA; float2* dst = bufB;
  #pragma unroll 1
  for (int st = 0; st < 12; ++st) {
    const int n  = NFFT >> st;
    const float tw = 6.2831853071795864f / (float)n;  // inverse: conjugated twiddles
    #pragma unroll
    for (int jj = 0; jj < 8; ++jj) {
      const int j = tid + jj * 256;
      const int p = j >> st;
      const int q = j & ((1 << st) - 1);
      float2 a = src[q + (p << st)];
      float2 b = src[q + (p << st) + 2048];
      float sn, cs; __sincosf(tw * (float)p, &sn, &cs);
      float2 dif = make_float2(a.x - b.x, a.y - b.y);
      dst[q + (p << (st + 1))]             = make_float2(a.x + b.x, a.y + b.y);
      dst[q + (p << (st + 1)) + (1 << st)] = make_float2(dif.x*cs - dif.y*sn, dif.x*sn + dif.y*cs);
    }
    __syncthreads();
    float2* t = src; src = dst; dst = t;
  }
  const float scale = 1.0f / (float)NFFT;
  for (int j = tid; j < NFFT; j += 256)
    out[(size_t)bo * NFFT + j] = src[j].x * scale;
}

extern "C" void kernel_launch(void* const* d_in, const int* in_sizes, int n_in,
                              void* d_out, int out_size, void* d_ws, size_t ws_size,
                              hipStream_t stream) {
  const float* x   = (const float*)d_in[0];
  const float* wr  = (const float*)d_in[1];
  const float* wi  = (const float*)d_in[2];
  const float* br  = (const float*)d_in[3];
  const float* bim = (const float*)d_in[4];
  float* out = (float*)d_out;

  // workspace layout: phi0 (4 KB) | zA (134.3 MB) | zB (134.3 MB)
  // w-transpose scratch lives in d_out (134.2 MB >= 67.1 MB), overwritten by K5 later.
  char* ws = (char*)d_ws;
  const size_t ZBYTES = (size_t)NSIG * HALF * sizeof(float2);  // 134,283,264
  float*  phi0 = (float*)ws;
  float2* zA   = (float2*)(ws + 4096);
  float2* zB   = (float2*)(ws + 4096 + ZBYTES);
  float2* wt   = (float2*)d_out;   // 2049*4096*8 = 67.1 MB, fits in d_out

  // K1: rfft + per-signal phase alignment -> zA[bi][k]
  k_rfft_phase<<<NSIG, 256, 0, stream>>>(x, zA, phi0);
  // K2a: zA (8192 x 2049) -> zB (2049 x 8192)
  k_transpose_f2<<<dim3((HALF + 31) / 32, NSIG / 32), 256, 0, stream>>>(zA, zB, NSIG, HALF);
  // K2b: w (4096 x 2049, two float arrays) -> wt (2049 x 4096 float2)
  k_transpose_w<<<dim3((HALF + 31) / 32, NIO / 32), 256, 0, stream>>>(wr, wi, wt, NIO, HALF);
  // K3: per-mode GEMM + bias + output rotation -> zA[k][bo]
  k_gemm_mode<<<HALF, 256, 0, stream>>>(zB, wt, br, bim, phi0, zA);
  // K4: zA (2049 x 8192) -> zB (8192 x 2049)
  k_transpose_f2<<<dim3(NSIG / 32, (HALF + 31) / 32), 256, 0, stream>>>(zA, zB, HALF, NSIG);
  // K5: irfft -> out
  k_irfft<<<NSIG, 256, 0, stream>>>(zB, out);
}